// Round 1
// baseline (1055.715 us; speedup 1.0000x reference)
//
#include <hip/hip_runtime.h>

// ---------------------------------------------------------------------------
// AttentionBlock: GroupNorm(8) -> QKV (C=512) -> softmax attention over
// N=H*W=1024 tokens per batch (B=32) -> proj + residual.
// All matmuls in bf16 MFMA (16x16x32), fp32 accum. absmax threshold 0.11;
// expected error ~1e-2.
//
// Workspace layout (needs ~98 MB):
//   [0      )  stats: float2 (mean, rstd) per (b,g), 256*2 floats
//   [4096   )  bias_all: float[1536]  (bq|bk|bv)
//   [16384  )  WT: bf16 [4][512][512]  (Wq^T|Wk^T|Wv^T|Wp^T, row=n, col=k)
//   [2113536)  Q bf16 [32768][512]  (overwritten in-place by attention O)
//   [+32MB  )  K bf16
//   [+64MB  )  V bf16
// xn (bf16, 32 MB) lives in the first half of d_out; it is fully dead before
// the final GEMM rewrites d_out.
// ---------------------------------------------------------------------------

typedef unsigned short ushort_t;
typedef unsigned int u32;
typedef __attribute__((ext_vector_type(8))) short bf16x8;
typedef __attribute__((ext_vector_type(4))) float f32x4;

#define M_TOTAL 32768   // B * H * W
#define C_DIM 512

__device__ __forceinline__ ushort_t f2bf(float f) {
  union { float f; u32 u; } v; v.f = f;
  u32 r = v.u + 0x7fffu + ((v.u >> 16) & 1u);   // RNE; inputs are finite
  return (ushort_t)(r >> 16);
}

__device__ __forceinline__ void g2lds16(const void* gsrc, void* lds_base_uniform) {
  // async 16B/lane global->LDS; LDS dest is wave-uniform base + lane*16
  __builtin_amdgcn_global_load_lds(
      (const __attribute__((address_space(1))) u32*)gsrc,
      (__attribute__((address_space(3))) u32*)lds_base_uniform, 16, 0, 0);
}

// ---------------------------------------------------------------------------
// Pack weights to bf16 transposed [n][k] (+ concat QKV biases).
__global__ __launch_bounds__(256) void pack_w(
    const float* __restrict__ Wq, const float* __restrict__ Wk,
    const float* __restrict__ Wv, const float* __restrict__ Wp,
    const float* __restrict__ bq, const float* __restrict__ bk,
    const float* __restrict__ bv,
    ushort_t* __restrict__ WT, float* __restrict__ bias_all) {
  const int tid = blockIdx.x * 256 + threadIdx.x;        // 4*512*512 total
  const int mat = tid >> 18, rem = tid & 262143;
  const int n = rem >> 9, k = rem & 511;
  const float* Wsrc = (mat == 0) ? Wq : (mat == 1) ? Wk : (mat == 2) ? Wv : Wp;
  WT[tid] = f2bf(Wsrc[(k << 9) | n]);                    // W is [k][n] row-major
  if (tid < 512) {
    bias_all[tid] = bq[tid];
    bias_all[512 + tid] = bk[tid];
    bias_all[1024 + tid] = bv[tid];
  }
}

// ---------------------------------------------------------------------------
// GroupNorm stats: one block per (b,g); reduce 32*32*64 = 65536 elements.
__global__ __launch_bounds__(256) void gn_stats(const float* __restrict__ x,
                                                float* __restrict__ stats) {
  const int bg = blockIdx.x, b = bg >> 3, g = bg & 7;
  const float* base = x + (b << 19) + (g << 6);
  const int t = threadIdx.x;
  const int c4 = (t & 15) << 2, hw0 = t >> 4;
  float s = 0.f, s2 = 0.f;
  for (int i = 0; i < 64; ++i) {
    const float4 v = *(const float4*)(base + ((hw0 + (i << 4)) << 9) + c4);
    s  += v.x + v.y + v.z + v.w;
    s2 += v.x * v.x + v.y * v.y + v.z * v.z + v.w * v.w;
  }
#pragma unroll
  for (int m = 32; m >= 1; m >>= 1) { s += __shfl_xor(s, m); s2 += __shfl_xor(s2, m); }
  __shared__ float rs[4], rs2[4];
  const int w = t >> 6;
  if ((t & 63) == 0) { rs[w] = s; rs2[w] = s2; }
  __syncthreads();
  if (t == 0) {
    const float S = rs[0] + rs[1] + rs[2] + rs[3];
    const float S2 = rs2[0] + rs2[1] + rs2[2] + rs2[3];
    const float inv = 1.0f / 65536.0f;
    const float mean = S * inv;
    const float var = S2 * inv - mean * mean;
    stats[bg * 2] = mean;
    stats[bg * 2 + 1] = rsqrtf(var + 1e-3f);
  }
}

// ---------------------------------------------------------------------------
// Apply GN affine, write xn as bf16. float4 in, ushort4 out.
__global__ __launch_bounds__(256) void gn_apply(
    const float* __restrict__ x, const float* __restrict__ stats,
    const float* __restrict__ gamma, const float* __restrict__ beta,
    ushort_t* __restrict__ xn) {
  const int i4 = blockIdx.x * 256 + threadIdx.x;
  const int e = i4 << 2;
  const int c = e & 511;
  const int b = e >> 19;
  const int g = c >> 6;
  const float2 st = *(const float2*)(stats + (((b << 3) | g) << 1));
  const float4 xv = *(const float4*)(x + e);
  const float4 gv = *(const float4*)(gamma + c);
  const float4 bv = *(const float4*)(beta + c);
  ushort4 o;
  o.x = f2bf((xv.x - st.x) * st.y * gv.x + bv.x);
  o.y = f2bf((xv.y - st.x) * st.y * gv.y + bv.y);
  o.z = f2bf((xv.z - st.x) * st.y * gv.z + bv.z);
  o.w = f2bf((xv.w - st.x) * st.y * gv.w + bv.w);
  *(ushort4*)(xn + e) = o;
}

// ---------------------------------------------------------------------------
// bf16 GEMM, B^T layout: C[m][n] = sum_k A[m][k]*BT[n][k] + bias[n].
// 128x128 tile, BK=32, 4 waves (2x2), 4x4 16x16 fragments per wave.
// FINAL=false: N=1536, write bf16 into Q|K|V (mat = n>>9).
// FINAL=true : N=512,  write fp32 out = resid + val.
template <bool FINAL>
__global__ __launch_bounds__(256) void gemm_bt(
    const ushort_t* __restrict__ A, const ushort_t* __restrict__ BT,
    const float* __restrict__ bias, ushort_t* __restrict__ Cq,
    float* __restrict__ Cf, const float* __restrict__ resid) {
  __shared__ __align__(16) char smem[16384];   // A tile 8KB | B tile 8KB
  const int tid = threadIdx.x;
  const int w = tid >> 6, lane = tid & 63;
  const int l15 = lane & 15, lhi = lane >> 4;
  const int wm = w >> 1, wn = w & 1;
  const int m0 = blockIdx.x * 128, n0 = blockIdx.y * 128;
  f32x4 acc[4][4] = {};

  for (int k0 = 0; k0 < C_DIM; k0 += 32) {
#pragma unroll
    for (int st = 0; st < 2; ++st) {   // 512 16B-chunks per tile, 2/thread
      const int q = st * 256 + tid;
      const int r = q >> 2, p = q & 3;
      g2lds16((const char*)(A + (m0 + r) * C_DIM + k0) + p * 16,
              smem + (st * 256 + w * 64) * 16);
      g2lds16((const char*)(BT + (n0 + r) * C_DIM + k0) + p * 16,
              smem + 8192 + (st * 256 + w * 64) * 16);
    }
    __syncthreads();   // compiler drains vmcnt before barrier
    bf16x8 aF[4], bF[4];
#pragma unroll
    for (int fm = 0; fm < 4; ++fm)
      aF[fm] = *(const bf16x8*)(smem + (wm * 64 + fm * 16 + l15) * 64 + lhi * 16);
#pragma unroll
    for (int fn = 0; fn < 4; ++fn)
      bF[fn] = *(const bf16x8*)(smem + 8192 + (wn * 64 + fn * 16 + l15) * 64 + lhi * 16);
#pragma unroll
    for (int fm = 0; fm < 4; ++fm)
#pragma unroll
      for (int fn = 0; fn < 4; ++fn)
        acc[fm][fn] = __builtin_amdgcn_mfma_f32_16x16x32_bf16(aF[fm], bF[fn],
                                                              acc[fm][fn], 0, 0, 0);
    __syncthreads();
  }

#pragma unroll
  for (int fn = 0; fn < 4; ++fn) {
    const int col = n0 + wn * 64 + fn * 16 + l15;
    const float bb = bias[col];
#pragma unroll
    for (int fm = 0; fm < 4; ++fm) {
#pragma unroll
      for (int j = 0; j < 4; ++j) {
        const int row = m0 + wm * 64 + fm * 16 + lhi * 4 + j;
        const float val = acc[fm][fn][j] + bb;
        if (FINAL) {
          Cf[row * C_DIM + col] = resid[row * C_DIM + col] + val;
        } else {
          const int mat = col >> 9, c = col & 511;
          Cq[mat * (M_TOTAL * C_DIM) + row * C_DIM + c] = f2bf(val);
        }
      }
    }
  }
}

// ---------------------------------------------------------------------------
// Flash attention, one block per (q-tile of 64 rows, batch). 8 waves.
// KB=32 kv-rows per iteration, 32 iterations. Online softmax (wave 0) runs
// concurrently with V-transpose staging (waves 1-7). O overwrites Q in place
// (each block touches only its own 64 rows of Q/O).
__global__ __launch_bounds__(512) void attn_fused(
    const ushort_t* Qm, const ushort_t* __restrict__ Km,
    const ushort_t* __restrict__ Vm, ushort_t* Om) {
  __shared__ __align__(16) ushort_t kv[20480];  // K tile [32][520] / VT [512][40]
  __shared__ float Ssm[64 * 33];
  __shared__ __align__(16) ushort_t Psm[64 * 40];
  __shared__ float mrow[64], lrow[64], frow[64];

  const int tid = threadIdx.x, w = tid >> 6, lane = tid & 63;
  const int l15 = lane & 15, lhi = lane >> 4;
  const int batch = blockIdx.y, qt = blockIdx.x;
  const int rowbase = batch * 1024 + qt * 64;
  const int qi = w & 3, ki = w >> 2;             // S subtile (4 qi x 2 ki)
  const float scale = 0.044194173824159216f;     // 512^-0.5

  f32x4 acc[4][4] = {};
  if (tid < 64) { mrow[tid] = -3e38f; lrow[tid] = 0.f; }
  __syncthreads();

  const ushort_t* qbase = Qm + (rowbase + qi * 16 + l15) * C_DIM;

  for (int kt = 0; kt < 32; ++kt) {
    const int krow = batch * 1024 + kt * 32;
    // ---- stage K tile [32][512] -> kv[32][520] (padded, conflict-free reads)
#pragma unroll
    for (int i = 0; i < 4; ++i) {
      const int ch = tid + i * 512;              // 2048 chunks of 8 elems
      const int r = ch >> 6, c8 = (ch & 63) * 8;
      *(bf16x8*)(&kv[r * 520 + c8]) = *(const bf16x8*)(Km + (krow + r) * C_DIM + c8);
    }
    __syncthreads();
    // ---- S = scale * Q K^T  (each wave: one 16x16 subtile, K=512)
    {
      f32x4 s = {};
      const ushort_t* kb = &kv[(ki * 16 + l15) * 520 + lhi * 8];
#pragma unroll
      for (int kc = 0; kc < 16; ++kc) {
        const bf16x8 aQ = *(const bf16x8*)(qbase + kc * 32 + lhi * 8);
        const bf16x8 bK = *(const bf16x8*)(kb + kc * 32);
        s = __builtin_amdgcn_mfma_f32_16x16x32_bf16(aQ, bK, s, 0, 0, 0);
      }
      const int sc = ki * 16 + l15;
#pragma unroll
      for (int j = 0; j < 4; ++j)
        Ssm[(qi * 16 + lhi * 4 + j) * 33 + sc] = s[j] * scale;
    }
    __syncthreads();
    // ---- wave 0: online softmax; waves 1-7: stage V^T into kv[512][40]
    if (tid < 64) {
      const int r = tid;
      const float m_old = mrow[r];
      float tm = -3e38f;
      for (int j = 0; j < 32; ++j) tm = fmaxf(tm, Ssm[r * 33 + j]);
      const float m_new = fmaxf(m_old, tm);
      const float f = __expf(m_old - m_new);
      float lsum = 0.f;
      for (int j = 0; j < 32; ++j) {
        const float p = __expf(Ssm[r * 33 + j] - m_new);
        lsum += p;
        Psm[r * 40 + j] = f2bf(p);
      }
      mrow[r] = m_new;
      frow[r] = f;
      lrow[r] = lrow[r] * f + lsum;
    } else {
      const int t = tid - 64;                    // 448 threads
#pragma unroll
      for (int i = 0; i < 5; ++i) {
        const int ch = t + i * 448;
        if (ch < 2048) {
          const int r = ch >> 6, c8 = (ch & 63) * 8;
          const bf16x8 vv = *(const bf16x8*)(Vm + (krow + r) * C_DIM + c8);
#pragma unroll
          for (int j = 0; j < 8; ++j) kv[(c8 + j) * 40 + r] = (ushort_t)vv[j];
        }
      }
    }
    __syncthreads();
    // ---- rescale accumulators, then O += P @ V (each wave: 64 channels)
    {
      float fr[4][4];
#pragma unroll
      for (int fm = 0; fm < 4; ++fm)
#pragma unroll
        for (int j = 0; j < 4; ++j) fr[fm][j] = frow[fm * 16 + lhi * 4 + j];
#pragma unroll
      for (int fm = 0; fm < 4; ++fm)
#pragma unroll
        for (int fn = 0; fn < 4; ++fn)
#pragma unroll
          for (int j = 0; j < 4; ++j) acc[fm][fn][j] *= fr[fm][j];
      bf16x8 aP[4], bV[4];
#pragma unroll
      for (int fm = 0; fm < 4; ++fm)
        aP[fm] = *(const bf16x8*)(&Psm[(fm * 16 + l15) * 40 + lhi * 8]);
#pragma unroll
      for (int fn = 0; fn < 4; ++fn)
        bV[fn] = *(const bf16x8*)(&kv[(w * 64 + fn * 16 + l15) * 40 + lhi * 8]);
#pragma unroll
      for (int fm = 0; fm < 4; ++fm)
#pragma unroll
        for (int fn = 0; fn < 4; ++fn)
          acc[fm][fn] = __builtin_amdgcn_mfma_f32_16x16x32_bf16(aP[fm], bV[fn],
                                                                acc[fm][fn], 0, 0, 0);
    }
    __syncthreads();   // protect kv/Ssm/Psm before next iteration
  }
  // ---- epilogue: O = acc / l, bf16, in place over Q
  float linv[4][4];
#pragma unroll
  for (int fm = 0; fm < 4; ++fm)
#pragma unroll
    for (int j = 0; j < 4; ++j) linv[fm][j] = 1.0f / lrow[fm * 16 + lhi * 4 + j];
#pragma unroll
  for (int fm = 0; fm < 4; ++fm)
#pragma unroll
    for (int fn = 0; fn < 4; ++fn) {
      const int col = w * 64 + fn * 16 + l15;
#pragma unroll
      for (int j = 0; j < 4; ++j) {
        const int row = fm * 16 + lhi * 4 + j;
        Om[(rowbase + row) * C_DIM + col] = f2bf(acc[fm][fn][j] * linv[fm][j]);
      }
    }
}

// ---------------------------------------------------------------------------
extern "C" void kernel_launch(void* const* d_in, const int* in_sizes, int n_in,
                              void* d_out, int out_size, void* d_ws, size_t ws_size,
                              hipStream_t stream) {
  const float* x     = (const float*)d_in[0];
  const float* gamma = (const float*)d_in[1];
  const float* beta  = (const float*)d_in[2];
  const float* Wq    = (const float*)d_in[3];
  const float* bq    = (const float*)d_in[4];
  const float* Wk    = (const float*)d_in[5];
  const float* bk    = (const float*)d_in[6];
  const float* Wv    = (const float*)d_in[7];
  const float* bv    = (const float*)d_in[8];
  const float* Wp    = (const float*)d_in[9];
  const float* bp    = (const float*)d_in[10];
  float* out = (float*)d_out;
  char* ws = (char*)d_ws;

  float* stats       = (float*)ws;                    // 2 KB
  float* bias_all    = (float*)(ws + 4096);           // 6 KB
  ushort_t* WT       = (ushort_t*)(ws + 16384);       // 2 MB (4x 512x512 bf16)
  ushort_t* Qb       = (ushort_t*)(ws + 2113536);     // 32 MB
  ushort_t* Kb       = Qb + 16777216;                 // 32 MB
  ushort_t* Vb       = Kb + 16777216;                 // 32 MB (end ~98 MB)
  ushort_t* xn       = (ushort_t*)d_out;              // 32 MB of d_out, dead
                                                      // before final GEMM

  pack_w<<<4096, 256, 0, stream>>>(Wq, Wk, Wv, Wp, bq, bk, bv, WT, bias_all);
  gn_stats<<<256, 256, 0, stream>>>(x, stats);
  gn_apply<<<16384, 256, 0, stream>>>(x, stats, gamma, beta, xn);
  gemm_bt<false><<<dim3(256, 12), 256, 0, stream>>>(xn, WT, bias_all, Qb,
                                                    nullptr, nullptr);
  attn_fused<<<dim3(16, 32), 512, 0, stream>>>(Qb, Kb, Vb, Qb);  // O over Q
  gemm_bt<true><<<dim3(256, 4), 256, 0, stream>>>(Qb, WT + 3 * 262144, bp,
                                                  nullptr, out, x);
}

// Round 2
// 455.960 us; speedup vs baseline: 2.3154x; 2.3154x over previous
//
#include <hip/hip_runtime.h>

// ---------------------------------------------------------------------------
// AttentionBlock: GroupNorm(8) -> QKV (C=512) -> softmax attention over
// N=H*W=1024 tokens per batch (B=32) -> proj + residual.
// bf16 MFMA (16x16x32), fp32 accum. absmax threshold 0.11; measured ~0.03.
//
// V is produced TRANSPOSED ([b][ch][kv]) directly by a GEMM variant so the
// attention PV step reads B-fragments straight from global (no LDS transpose).
// K tile is staged via global_load_lds with XOR-swizzle (conflict-free
// ds_read_b128); softmax is wave-parallel and in-register (log2 domain).
// ---------------------------------------------------------------------------

typedef unsigned short ushort_t;
typedef unsigned int u32;
typedef __attribute__((ext_vector_type(8))) short bf16x8;
typedef __attribute__((ext_vector_type(4))) float f32x4;

#define M_TOTAL 32768   // B * H * W
#define C_DIM 512

__device__ __forceinline__ ushort_t f2bf(float f) {
  union { float f; u32 u; } v; v.f = f;
  u32 r = v.u + 0x7fffu + ((v.u >> 16) & 1u);   // RNE; inputs are finite
  return (ushort_t)(r >> 16);
}

__device__ __forceinline__ void g2lds16(const void* gsrc, void* lds_base_uniform) {
  __builtin_amdgcn_global_load_lds(
      (const __attribute__((address_space(1))) u32*)gsrc,
      (__attribute__((address_space(3))) u32*)lds_base_uniform, 16, 0, 0);
}

// ---------------------------------------------------------------------------
// Pack weights to bf16 transposed [n][k] (+ concat QKV biases).
__global__ __launch_bounds__(256) void pack_w(
    const float* __restrict__ Wq, const float* __restrict__ Wk,
    const float* __restrict__ Wv, const float* __restrict__ Wp,
    const float* __restrict__ bq, const float* __restrict__ bk,
    const float* __restrict__ bv,
    ushort_t* __restrict__ WT, float* __restrict__ bias_all) {
  const int tid = blockIdx.x * 256 + threadIdx.x;        // 4*512*512 total
  const int rem = tid & 262143;
  const int mat = tid >> 18;
  const int n = rem >> 9, k = rem & 511;
  const float* Wsrc = (mat == 0) ? Wq : (mat == 1) ? Wk : (mat == 2) ? Wv : Wp;
  WT[tid] = f2bf(Wsrc[(k << 9) | n]);                    // W is [k][n] row-major
  if (tid < 512) {
    bias_all[tid] = bq[tid];
    bias_all[512 + tid] = bk[tid];
    bias_all[1024 + tid] = bv[tid];
  }
}

// ---------------------------------------------------------------------------
// GroupNorm stats: one block per (b,g); reduce 32*32*64 = 65536 elements.
__global__ __launch_bounds__(256) void gn_stats(const float* __restrict__ x,
                                                float* __restrict__ stats) {
  const int bg = blockIdx.x, b = bg >> 3, g = bg & 7;
  const float* base = x + (b << 19) + (g << 6);
  const int t = threadIdx.x;
  const int c4 = (t & 15) << 2, hw0 = t >> 4;
  float s = 0.f, s2 = 0.f;
  for (int i = 0; i < 64; ++i) {
    const float4 v = *(const float4*)(base + ((hw0 + (i << 4)) << 9) + c4);
    s  += v.x + v.y + v.z + v.w;
    s2 += v.x * v.x + v.y * v.y + v.z * v.z + v.w * v.w;
  }
#pragma unroll
  for (int m = 32; m >= 1; m >>= 1) { s += __shfl_xor(s, m); s2 += __shfl_xor(s2, m); }
  __shared__ float rs[4], rs2[4];
  const int w = t >> 6;
  if ((t & 63) == 0) { rs[w] = s; rs2[w] = s2; }
  __syncthreads();
  if (t == 0) {
    const float S = rs[0] + rs[1] + rs[2] + rs[3];
    const float S2 = rs2[0] + rs2[1] + rs2[2] + rs2[3];
    const float inv = 1.0f / 65536.0f;
    const float mean = S * inv;
    const float var = S2 * inv - mean * mean;
    stats[bg * 2] = mean;
    stats[bg * 2 + 1] = rsqrtf(var + 1e-3f);
  }
}

// ---------------------------------------------------------------------------
// Apply GN affine, write xn as bf16.
__global__ __launch_bounds__(256) void gn_apply(
    const float* __restrict__ x, const float* __restrict__ stats,
    const float* __restrict__ gamma, const float* __restrict__ beta,
    ushort_t* __restrict__ xn) {
  const int i4 = blockIdx.x * 256 + threadIdx.x;
  const int e = i4 << 2;
  const int c = e & 511;
  const int b = e >> 19;
  const int g = c >> 6;
  const float2 st = *(const float2*)(stats + (((b << 3) | g) << 1));
  const float4 xv = *(const float4*)(x + e);
  const float4 gv = *(const float4*)(gamma + c);
  const float4 bv = *(const float4*)(beta + c);
  ushort4 o;
  o.x = f2bf((xv.x - st.x) * st.y * gv.x + bv.x);
  o.y = f2bf((xv.y - st.x) * st.y * gv.y + bv.y);
  o.z = f2bf((xv.z - st.x) * st.y * gv.z + bv.z);
  o.w = f2bf((xv.w - st.x) * st.y * gv.w + bv.w);
  *(ushort4*)(xn + e) = o;
}

// ---------------------------------------------------------------------------
// bf16 GEMM, B^T layout: C[m][n] = sum_k A[m][k]*BT[n][k] + bias.
// 128x128 tile, BK=32, 4 waves (2x2), 4x4 16x16 fragments per wave.
// MODE 0: N=1024 (Q|K), bias[col], write bf16 row-major into Q|K.
// MODE 1: M=512 (ch), N=32768 (tokens), bias[row], write bf16 V^T
//         [b][ch][kv] (per-batch column-major V).
// MODE 2: N=512, bias[col], write fp32 out = resid + val.
template <int MODE>
__global__ __launch_bounds__(256) void gemm_bt(
    const ushort_t* __restrict__ A, const ushort_t* __restrict__ BT,
    const float* __restrict__ bias, ushort_t* __restrict__ Cq,
    float* __restrict__ Cf, const float* __restrict__ resid) {
  __shared__ __align__(16) char smem[16384];   // A tile 8KB | B tile 8KB
  const int tid = threadIdx.x;
  const int w = tid >> 6, lane = tid & 63;
  const int l15 = lane & 15, lhi = lane >> 4;
  const int wm = w >> 1, wn = w & 1;
  const int m0 = blockIdx.x * 128, n0 = blockIdx.y * 128;
  f32x4 acc[4][4] = {};

  for (int k0 = 0; k0 < C_DIM; k0 += 32) {
#pragma unroll
    for (int st = 0; st < 2; ++st) {   // 512 16B-chunks per tile, 2/thread
      const int q = st * 256 + tid;
      const int r = q >> 2, p = q & 3;
      g2lds16((const char*)(A + (m0 + r) * C_DIM + k0) + p * 16,
              smem + (st * 256 + w * 64) * 16);
      g2lds16((const char*)(BT + (n0 + r) * C_DIM + k0) + p * 16,
              smem + 8192 + (st * 256 + w * 64) * 16);
    }
    __syncthreads();
    bf16x8 aF[4], bF[4];
#pragma unroll
    for (int fm = 0; fm < 4; ++fm)
      aF[fm] = *(const bf16x8*)(smem + (wm * 64 + fm * 16 + l15) * 64 + lhi * 16);
#pragma unroll
    for (int fn = 0; fn < 4; ++fn)
      bF[fn] = *(const bf16x8*)(smem + 8192 + (wn * 64 + fn * 16 + l15) * 64 + lhi * 16);
#pragma unroll
    for (int fm = 0; fm < 4; ++fm)
#pragma unroll
      for (int fn = 0; fn < 4; ++fn)
        acc[fm][fn] = __builtin_amdgcn_mfma_f32_16x16x32_bf16(aF[fm], bF[fn],
                                                              acc[fm][fn], 0, 0, 0);
    __syncthreads();
  }

  if constexpr (MODE == 1) {
    // V^T output: row = channel (bias row), col = token.
#pragma unroll
    for (int fm = 0; fm < 4; ++fm) {
#pragma unroll
      for (int j = 0; j < 4; ++j) {
        const int row = m0 + wm * 64 + fm * 16 + lhi * 4 + j;
        const float bb = bias[row];
#pragma unroll
        for (int fn = 0; fn < 4; ++fn) {
          const int col = n0 + wn * 64 + fn * 16 + l15;
          Cq[(col >> 10) * 524288 + row * 1024 + (col & 1023)] =
              f2bf(acc[fm][fn][j] + bb);
        }
      }
    }
  } else {
#pragma unroll
    for (int fn = 0; fn < 4; ++fn) {
      const int col = n0 + wn * 64 + fn * 16 + l15;
      const float bb = bias[col];
#pragma unroll
      for (int fm = 0; fm < 4; ++fm) {
#pragma unroll
        for (int j = 0; j < 4; ++j) {
          const int row = m0 + wm * 64 + fm * 16 + lhi * 4 + j;
          const float val = acc[fm][fn][j] + bb;
          if constexpr (MODE == 2) {
            Cf[row * C_DIM + col] = resid[row * C_DIM + col] + val;
          } else {
            const int mat = col >> 9, c = col & 511;
            Cq[mat * (M_TOTAL * C_DIM) + row * C_DIM + c] = f2bf(val);
          }
        }
      }
    }
  }
}

// ---------------------------------------------------------------------------
// Flash attention v2. Grid: 512 blocks (XCD-chunk swizzled), 512 threads.
// Per block: 64 q-rows, loop 16 tiles of 64 kv rows. 8 waves: qi=w&3 (16-row
// q group for QK^T), ki=w>>2 (32-kv half). Q in registers; K staged in LDS
// (XOR-swizzled, global_load_lds w=16); V read as fragments from global V^T;
// softmax wave-parallel, in-register, log2 domain. O overwrites Q in place.
#define SCALE2 0.063758716f   // 512^-0.5 * log2(e)
__global__ __launch_bounds__(512) void attn_v2(
    const ushort_t* Qm, const ushort_t* __restrict__ Km,
    const ushort_t* __restrict__ VTm, ushort_t* Om) {
  __shared__ __align__(16) ushort_t Ks[32768];   // 64 rows x 1024B, swizzled
  __shared__ __align__(16) ushort_t Psm[64 * 72];
  __shared__ float red_m[128], red_l[128];
  __shared__ float mrow[64], lrow[64], frow[64];

  const int tid = threadIdx.x, w = tid >> 6, lane = tid & 63;
  const int l15 = lane & 15, lhi = lane >> 4;
  const int qi = w & 3, ki = w >> 2;
  const int bid = blockIdx.x;
  const int L = (bid & 7) * 64 + (bid >> 3);     // XCD-chunk swizzle (512%8==0)
  const int batch = L >> 4, qt = L & 15;
  const int rowbase = batch * 1024 + qt * 64;

  // Q fragments: rows qi*16 + l15, all 512 channels (read once)
  bf16x8 qf[16];
  {
    const ushort_t* qb = Qm + (rowbase + qi * 16 + l15) * C_DIM + lhi * 8;
#pragma unroll
    for (int kc = 0; kc < 16; ++kc) qf[kc] = *(const bf16x8*)(qb + kc * 32);
  }
  f32x4 acc[4][4] = {};
  if (tid < 64) { mrow[tid] = -1e30f; lrow[tid] = 0.f; }

  const int swz = (l15 & 7) << 4;
  const char* Kbase = (const char*)(Km + (size_t)batch * 1024 * C_DIM);
  const ushort_t* VTb = VTm + batch * 524288 + (w * 64 + l15) * 1024 + lhi * 8;

#define STAGE_K(kt_)                                                          \
  {                                                                           \
    _Pragma("unroll")                                                         \
    for (int i = 0; i < 8; ++i) {                                             \
      const int c = i * 512 + tid;                                            \
      const int row = c >> 6, colp = (c & 63) << 4;                           \
      g2lds16(Kbase + ((kt_) * 64 + row) * 1024 + (colp ^ ((row & 7) << 4)),  \
              (char*)Ks + ((i * 512 + w * 64) << 4));                         \
    }                                                                         \
  }

  STAGE_K(0);
  __syncthreads();   // B0 for kt=0 (drains staging; covers mrow init)

  for (int kt = 0; kt < 16; ++kt) {
    // ---- phase 1: S = Q K^T, two 16x16 subtiles (kv halves of this wave)
    f32x4 s0 = {}, s1 = {};
    {
      const int r0 = (ki * 32 + l15) << 10;
      const int r1 = r0 + (16 << 10);
#pragma unroll
      for (int kc = 0; kc < 16; ++kc) {
        const bf16x8 k0 = *(const bf16x8*)((const char*)Ks + r0 + ((kc * 64 + lhi * 16) ^ swz));
        s0 = __builtin_amdgcn_mfma_f32_16x16x32_bf16(qf[kc], k0, s0, 0, 0, 0);
      }
#pragma unroll
      for (int kc = 0; kc < 16; ++kc) {
        const bf16x8 k1 = *(const bf16x8*)((const char*)Ks + r1 + ((kc * 64 + lhi * 16) ^ swz));
        s1 = __builtin_amdgcn_mfma_f32_16x16x32_bf16(qf[kc], k1, s1, 0, 0, 0);
      }
    }
#pragma unroll
    for (int j = 0; j < 4; ++j) { s0[j] *= SCALE2; s1[j] *= SCALE2; }
    // row-max over this wave's 32 kv (reduce over l15 lanes)
    float pm[4];
#pragma unroll
    for (int j = 0; j < 4; ++j) {
      float t = fmaxf(s0[j], s1[j]);
      t = fmaxf(t, __shfl_xor(t, 1));
      t = fmaxf(t, __shfl_xor(t, 2));
      t = fmaxf(t, __shfl_xor(t, 4));
      t = fmaxf(t, __shfl_xor(t, 8));
      pm[j] = t;
    }
    if (l15 == 0) {
#pragma unroll
      for (int j = 0; j < 4; ++j)
        red_m[ki * 64 + qi * 16 + lhi * 4 + j] = pm[j];
    }
    __syncthreads();   // B1
    // ---- phase 2: m_new, P = exp2(s - m), partial row-sums
    float mnew[4], f_loc[4], ls[4];
#pragma unroll
    for (int j = 0; j < 4; ++j) {
      const int r = qi * 16 + lhi * 4 + j;
      mnew[j] = fmaxf(mrow[r], fmaxf(red_m[r], red_m[64 + r]));
      const float p0 = exp2f(s0[j] - mnew[j]);
      const float p1 = exp2f(s1[j] - mnew[j]);
      Psm[r * 72 + ki * 32 + l15] = f2bf(p0);
      Psm[r * 72 + ki * 32 + 16 + l15] = f2bf(p1);
      float t = p0 + p1;
      t += __shfl_xor(t, 1);
      t += __shfl_xor(t, 2);
      t += __shfl_xor(t, 4);
      t += __shfl_xor(t, 8);
      ls[j] = t;
    }
    if (l15 == 0) {
#pragma unroll
      for (int j = 0; j < 4; ++j) {
        const int r = qi * 16 + lhi * 4 + j;
        red_l[ki * 64 + r] = ls[j];
        if (ki == 0) {
          f_loc[j] = exp2f(mrow[r] - mnew[j]);
          frow[r] = f_loc[j];
        }
      }
    }
    __syncthreads();   // B2
    // designated lanes commit running stats (read next iter, after B0+B1)
    if (ki == 0 && l15 == 0) {
#pragma unroll
      for (int j = 0; j < 4; ++j) {
        const int r = qi * 16 + lhi * 4 + j;
        mrow[r] = mnew[j];
        lrow[r] = lrow[r] * f_loc[j] + red_l[r] + red_l[64 + r];
      }
    }
    // prefetch next K tile; flight overlaps PV below, drained at B0
    if (kt + 1 < 16) STAGE_K(kt + 1);
    // ---- phase 3: rescale acc, O += P @ V (wave owns 64 output channels)
#pragma unroll
    for (int fm = 0; fm < 4; ++fm) {
      float fv[4];
#pragma unroll
      for (int j = 0; j < 4; ++j) fv[j] = frow[fm * 16 + lhi * 4 + j];
#pragma unroll
      for (int fn = 0; fn < 4; ++fn)
#pragma unroll
        for (int j = 0; j < 4; ++j) acc[fm][fn][j] *= fv[j];
    }
#pragma unroll
    for (int ks = 0; ks < 2; ++ks) {
      bf16x8 pa[4], vb[4];
#pragma unroll
      for (int fm = 0; fm < 4; ++fm)
        pa[fm] = *(const bf16x8*)(&Psm[(fm * 16 + l15) * 72 + ks * 32 + lhi * 8]);
#pragma unroll
      for (int fn = 0; fn < 4; ++fn)
        vb[fn] = *(const bf16x8*)(VTb + fn * 16384 + kt * 64 + ks * 32);
#pragma unroll
      for (int fm = 0; fm < 4; ++fm)
#pragma unroll
        for (int fn = 0; fn < 4; ++fn)
          acc[fm][fn] = __builtin_amdgcn_mfma_f32_16x16x32_bf16(pa[fm], vb[fn],
                                                                acc[fm][fn], 0, 0, 0);
    }
    __syncthreads();   // B0 for next iter (drains K staging)
  }
  // ---- epilogue: O = acc / l, bf16, in place over Q
  ushort_t* ob = Om + (size_t)rowbase * C_DIM + w * 64;
#pragma unroll
  for (int fm = 0; fm < 4; ++fm) {
#pragma unroll
    for (int j = 0; j < 4; ++j) {
      const int row = fm * 16 + lhi * 4 + j;
      const float li = 1.0f / lrow[row];
#pragma unroll
      for (int fn = 0; fn < 4; ++fn)
        ob[row * C_DIM + fn * 16 + l15] = f2bf(acc[fm][fn][j] * li);
    }
  }
}

// ---------------------------------------------------------------------------
extern "C" void kernel_launch(void* const* d_in, const int* in_sizes, int n_in,
                              void* d_out, int out_size, void* d_ws, size_t ws_size,
                              hipStream_t stream) {
  const float* x     = (const float*)d_in[0];
  const float* gamma = (const float*)d_in[1];
  const float* beta  = (const float*)d_in[2];
  const float* Wq    = (const float*)d_in[3];
  const float* bq    = (const float*)d_in[4];
  const float* Wk    = (const float*)d_in[5];
  const float* bk    = (const float*)d_in[6];
  const float* Wv    = (const float*)d_in[7];
  const float* bv    = (const float*)d_in[8];
  const float* Wp    = (const float*)d_in[9];
  const float* bp    = (const float*)d_in[10];
  float* out = (float*)d_out;
  char* ws = (char*)d_ws;

  float* stats       = (float*)ws;                    // 2 KB
  float* bias_all    = (float*)(ws + 4096);           // 6 KB
  ushort_t* WT       = (ushort_t*)(ws + 16384);       // 2 MB (4x 512x512 bf16)
  ushort_t* Qb       = (ushort_t*)(ws + 2113536);     // 32 MB
  ushort_t* Kb       = Qb + 16777216;                 // 32 MB
  ushort_t* VTb      = Kb + 16777216;                 // 32 MB: V^T [b][ch][kv]
  ushort_t* xn       = (ushort_t*)d_out;              // 32 MB of d_out, dead
                                                      // before final GEMM

  pack_w<<<4096, 256, 0, stream>>>(Wq, Wk, Wv, Wp, bq, bk, bv, WT, bias_all);
  gn_stats<<<256, 256, 0, stream>>>(x, stats);
  gn_apply<<<16384, 256, 0, stream>>>(x, stats, gamma, beta, xn);
  // Q|K: [32768 tokens] x [1024 cols]
  gemm_bt<0><<<dim3(256, 8), 256, 0, stream>>>(xn, WT, bias_all, Qb,
                                               nullptr, nullptr);
  // V^T: A = Wv^T (512 ch rows), B^T = xn (32768 tokens)
  gemm_bt<1><<<dim3(4, 256), 256, 0, stream>>>(WT + 2 * 262144, xn, bv, VTb,
                                               nullptr, nullptr);
  attn_v2<<<512, 512, 0, stream>>>(Qb, Kb, VTb, Qb);   // O over Q
  gemm_bt<2><<<dim3(256, 4), 256, 0, stream>>>(Qb, WT + 3 * 262144, bp,
                                               nullptr, out, x);
}